// Round 3
// baseline (2225.403 us; speedup 1.0000x reference)
//
#include <hip/hip_runtime.h>

#define D 128
#define BN_EPS 1e-5f

typedef _Float16 half8 __attribute__((ext_vector_type(8)));
typedef float f32x4 __attribute__((ext_vector_type(4)));
typedef unsigned short ushort_t;

// ---------------- fp16 pack/unpack helpers ----------------
__device__ __forceinline__ unsigned short f2h(float f) {
  union { _Float16 h; unsigned short u; } c;
  c.h = (_Float16)f;  // RNE
  return c.u;
}
__device__ __forceinline__ unsigned int packh(float lo, float hi) {
  return (unsigned int)f2h(lo) | ((unsigned int)f2h(hi) << 16);
}
__device__ __forceinline__ float h2f(unsigned int v) {
  union { unsigned short u; _Float16 h; } c;
  c.u = (unsigned short)v;
  return (float)c.h;
}
// non-temporal 8B load (edge-meta stream: don't evict the L2-resident h slice)
__device__ __forceinline__ uint2 ldnt_u2(const uint2* p) {
  union { unsigned long long q; uint2 v; } c;
  c.q = __builtin_nontemporal_load((const unsigned long long*)p);
  return c.v;
}

// ---------------------------------------------------------------------------
// Edge dtype sniffer (int64 vs int32 edge_index)
// ---------------------------------------------------------------------------
__global__ void k_detect(const int* __restrict__ ei, int* __restrict__ flag) {
  if (blockIdx.x == 0 && threadIdx.x == 0) {
    int is64 = 1;
    for (int i = 0; i < 16; i++)
      if (ei[2 * i + 1] != 0) is64 = 0;
    *flag = is64;
  }
}
__device__ __forceinline__ int load_src(const int* ei, int e, int i, int is64) {
  return is64 ? ei[2 * i] : ei[i];
}
__device__ __forceinline__ int load_dst(const int* ei, int e, int i, int is64) {
  return is64 ? ei[2 * e + 2 * i] : ei[e + i];
}

// ---------------------------------------------------------------------------
// Graph prep. Self-loop is materialized as a real CSR edge; rows padded to a
// multiple of 16 over (deg+1). Pad meta {0,0} gathers node 0 w/ weight 0.
// ---------------------------------------------------------------------------
__global__ void k_hist(const int* __restrict__ ei, int* __restrict__ cnt,
                       const int* __restrict__ flag, int e) {
  int i = blockIdx.x * blockDim.x + threadIdx.x;
  if (i < e) {
    int d = load_dst(ei, e, i, *flag);
    atomicAdd(&cnt[d], 1);
  }
}

__global__ void k_scan1(const int* __restrict__ cnt, int* __restrict__ excl,
                        int* __restrict__ bsum, int n) {
  __shared__ int s[256];
  int t = threadIdx.x;
  int base = blockIdx.x * 1024;
  int v[4];
  int tot = 0;
#pragma unroll
  for (int i = 0; i < 4; i++) {
    int idx = base + t * 4 + i;
    v[i] = (idx < n) ? ((cnt[idx] + 1 + 15) & ~15) : 0;  // deg+1 (self), pad-16
    tot += v[i];
  }
  s[t] = tot;
  __syncthreads();
#pragma unroll
  for (int off = 1; off < 256; off <<= 1) {
    int x = (t >= off) ? s[t - off] : 0;
    __syncthreads();
    s[t] += x;
    __syncthreads();
  }
  int run = s[t] - tot;
#pragma unroll
  for (int i = 0; i < 4; i++) {
    int idx = base + t * 4 + i;
    if (idx < n) excl[idx] = run;
    run += v[i];
  }
  if (t == 255) bsum[blockIdx.x] = s[255];
}

__global__ void k_scan2(int* bsum, int nb, int* row_ptr, int n) {
  if (blockIdx.x == 0 && threadIdx.x == 0) {
    int run = 0;
    for (int i = 0; i < nb; i++) {
      int t = bsum[i];
      bsum[i] = run;
      run += t;
    }
    row_ptr[n] = run;
  }
}

__global__ void k_scan3(const int* __restrict__ excl, const int* __restrict__ bsum,
                        int* __restrict__ row_ptr, int n) {
  int i = blockIdx.x * blockDim.x + threadIdx.x;
  if (i < n) row_ptr[i] = excl[i] + bsum[i >> 10];
}

__global__ void k_dinv(const int* __restrict__ cnt, float* __restrict__ dinv, int n) {
  int i = blockIdx.x * blockDim.x + threadIdx.x;
  if (i < n) dinv[i] = rsqrtf((float)(cnt[i] + 1));  // +1 self loop
}

// Edge meta: {.x = src*32 (byte offset into a 32B slice chunk), .y = w bits}
__global__ void k_scatter(const int* __restrict__ ei, const int* __restrict__ row_ptr,
                          int* __restrict__ fill, const float* __restrict__ dinv,
                          uint2* __restrict__ eh, const int* __restrict__ flag,
                          int e) {
  int i = blockIdx.x * blockDim.x + threadIdx.x;
  if (i < e) {
    int is64 = *flag;
    int s = load_src(ei, e, i, is64);
    int d = load_dst(ei, e, i, is64);
    int pos = row_ptr[d] + atomicAdd(&fill[d], 1);
    uint2 m;
    m.x = (unsigned int)s * 32u;
    m.y = __float_as_uint(dinv[s] * dinv[d]);
    eh[pos] = m;
  }
}

// self-loop edge at row_ptr[i]+cnt[i] (after k_scatter; same stream => ordered)
__global__ void k_self(const int* __restrict__ cnt, const int* __restrict__ row_ptr,
                       const float* __restrict__ dinv, uint2* __restrict__ eh,
                       int n) {
  int i = blockIdx.x * blockDim.x + threadIdx.x;
  if (i < n) {
    float di = dinv[i];
    uint2 m;
    m.x = (unsigned int)i * 32u;
    m.y = __float_as_uint(di * di);
    eh[row_ptr[i] + cnt[i]] = m;
  }
}

// ---------------------------------------------------------------------------
// W fp32 -> fp16 in MFMA-B-fragment-major layout: Wf[l][(k>>3)*128 + c][k&7]
// ---------------------------------------------------------------------------
__global__ void k_wconv(const float* __restrict__ W0, const float* __restrict__ Wmid,
                        const float* __restrict__ Wlast, ushort_t* __restrict__ Wf) {
  int i = blockIdx.x * 256 + threadIdx.x;
  if (i >= 6 * 16384) return;
  int l = i >> 14, r = i & 16383;
  int k = r >> 7, c = r & 127;
  const float* W = (l == 0) ? W0 : (l <= 4 ? Wmid + (size_t)(l - 1) * 16384 : Wlast);
  Wf[(size_t)l * 16384 + (((k >> 3) * 128 + c) << 3) + (k & 7)] = f2h(W[r]);
}

// ---------------------------------------------------------------------------
// Fused GEMM: x = epilogue(src) ; H = x @ W.
// fp16 feature tensors (Hh, Ag) are SLICE-MAJOR: [slice(=ch>>4)][node][16ch],
// 32B per node per slice, so the aggregation's gather working set per slice
// is n*32B = 3.2MB < 4MB (one XCD's L2).
//   mode 0: x = fp32 src (raw input, [node][128]), no BN, no Xh write
//   mode 1: x = relu(bn(src_sliced_fp16)); write XhNew
//   mode 2: x = relu(bn(src_sliced_fp16)) + XhPrev; write XhNew
// XhNew/XhPrev (residual stream) stay in [node][128] fp16-packed layout.
// ---------------------------------------------------------------------------
__global__ __launch_bounds__(256) void k_gemm(
    const void* __restrict__ src, const ushort_t* __restrict__ Wf,
    ushort_t* __restrict__ Hh, unsigned int* __restrict__ XhNew,
    const unsigned int* __restrict__ XhPrev, const float* __restrict__ stats,
    const float* __restrict__ gamma, const float* __restrict__ beta, int n,
    int mode) {
  __shared__ ushort_t As[16384];
  __shared__ ushort_t Ws[16384];
  const int t = threadIdx.x;
  const int rowBase = blockIdx.x * 128;
  const int off = t & 15;  // channel octet this thread stages (all 8 chunks)
  const size_t slice_stride = (size_t)n * 32;  // bytes per slice plane

  float sc[8], sh[8];
  if (mode >= 1) {
    float inv_n = 1.0f / (float)n;
#pragma unroll
    for (int j = 0; j < 8; j++) {
      int ch = off * 8 + j;
      float mean = stats[ch] * inv_n;
      float var = stats[128 + ch] * inv_n - mean * mean;
      if (var < 0.f) var = 0.f;
      float is = rsqrtf(var + BN_EPS);
      float s = gamma[ch] * is;
      sc[j] = s;
      sh[j] = beta[ch] - mean * s;
    }
  }

#pragma unroll
  for (int i = 0; i < 8; i++) {
    int c = t + i * 256;
    int row = c >> 4;
    int grow = rowBase + row;
    bool valid = grow < n;
    if (!valid) grow = n - 1;
    unsigned int pk[4];
    if (mode == 0) {
      const float* xp = (const float*)src + (size_t)grow * 128 + off * 8;
      float4 v0 = *(const float4*)xp;
      float4 v1 = *(const float4*)(xp + 4);
      pk[0] = packh(v0.x, v0.y);
      pk[1] = packh(v0.z, v0.w);
      pk[2] = packh(v1.x, v1.y);
      pk[3] = packh(v1.z, v1.w);
    } else {
      // sliced read: channels off*8..off*8+7 live in slice off>>1,
      // byte offset (off&1)*16 within the node's 32B chunk
      const char* ap = (const char*)src + (size_t)(off >> 1) * slice_stride +
                       (size_t)grow * 32 + (off & 1) * 16;
      uint4 av = *(const uint4*)ap;
      float v[8];
      v[0] = h2f(av.x & 0xffff); v[1] = h2f(av.x >> 16);
      v[2] = h2f(av.y & 0xffff); v[3] = h2f(av.y >> 16);
      v[4] = h2f(av.z & 0xffff); v[5] = h2f(av.z >> 16);
      v[6] = h2f(av.w & 0xffff); v[7] = h2f(av.w >> 16);
#pragma unroll
      for (int j = 0; j < 8; j++) v[j] = fmaxf(v[j] * sc[j] + sh[j], 0.f);
      if (mode == 2) {
        uint4 rv = *(const uint4*)(XhPrev + (size_t)grow * 64 + off * 4);
        v[0] += h2f(rv.x & 0xffff); v[1] += h2f(rv.x >> 16);
        v[2] += h2f(rv.y & 0xffff); v[3] += h2f(rv.y >> 16);
        v[4] += h2f(rv.z & 0xffff); v[5] += h2f(rv.z >> 16);
        v[6] += h2f(rv.w & 0xffff); v[7] += h2f(rv.w >> 16);
      }
      pk[0] = packh(v[0], v[1]);
      pk[1] = packh(v[2], v[3]);
      pk[2] = packh(v[4], v[5]);
      pk[3] = packh(v[6], v[7]);
      if (valid) *(uint4*)(XhNew + (size_t)grow * 64 + off * 4) = *(uint4*)pk;
    }
    *(uint4*)(&As[(off * 128 + row) * 8]) = *(uint4*)pk;
  }
#pragma unroll
  for (int i = 0; i < 8; i++) {
    int c = t + i * 256;
    *(uint4*)(&Ws[c * 8]) = *(const uint4*)(Wf + c * 8);
  }
  __syncthreads();

  const int wave = t >> 6, lane = t & 63;
  const int q = lane >> 4, ln = lane & 15;
  const int m0 = wave * 32;

  f32x4 acc[2][8];
#pragma unroll
  for (int mt = 0; mt < 2; mt++)
#pragma unroll
    for (int nt = 0; nt < 8; nt++) acc[mt][nt] = (f32x4){0.f, 0.f, 0.f, 0.f};

#pragma unroll
  for (int kk = 0; kk < 4; kk++) {
    int kg = kk * 4 + q;
    half8 a[2];
#pragma unroll
    for (int mt = 0; mt < 2; mt++)
      a[mt] = *(const half8*)(&As[(kg * 128 + m0 + mt * 16 + ln) * 8]);
    half8 b[8];
#pragma unroll
    for (int nt = 0; nt < 8; nt++)
      b[nt] = *(const half8*)(&Ws[(kg * 128 + nt * 16 + ln) * 8]);
#pragma unroll
    for (int mt = 0; mt < 2; mt++)
#pragma unroll
      for (int nt = 0; nt < 8; nt++)
        acc[mt][nt] =
            __builtin_amdgcn_mfma_f32_16x16x32_f16(a[mt], b[nt], acc[mt][nt], 0, 0, 0);
  }

  // sliced store: channel nt*16+ln -> slice nt, pos ln
#pragma unroll
  for (int mt = 0; mt < 2; mt++) {
#pragma unroll
    for (int r = 0; r < 4; r++) {
      int grow = rowBase + m0 + mt * 16 + q * 4 + r;
      if (grow < n) {
#pragma unroll
        for (int nt = 0; nt < 8; nt++) {
          ushort_t* hp = (ushort_t*)((char*)Hh + (size_t)nt * slice_stride +
                                     (size_t)grow * 32);
          hp[ln] = f2h(acc[mt][nt][r]);
        }
      }
    }
  }
}

// ---------------------------------------------------------------------------
// CHANNEL-SLICED aggregation, XCD-affine. slice = blockIdx.x & 7 — under the
// round-robin blockIdx->XCD dispatch, all blocks of a slice land on one XCD,
// whose 4MB L2 then holds that slice's entire h plane (n*32B = 3.2MB): the
// random per-edge gathers become L2 HITS. Edge meta is streamed with
// non-temporal loads so it doesn't evict the resident plane.
// Lane l: edge group g = l>>2 (16 edges/window), channel sublane c = l&3
// (4 fp16 ch = 8B of the 32B chunk). Per window: one 16-seg gather + one
// coalesced meta load + 4 fma_mix per lane. Reduce over lane bits 2..5.
// last=0: fp16 sliced out + BN stats.  last=1: fp32 [node][128] out.
// ---------------------------------------------------------------------------
__global__ __launch_bounds__(256) void k_agg(const char* __restrict__ hb,
                                             const int* __restrict__ row_ptr,
                                             const uint2* __restrict__ eh,
                                             const float* __restrict__ bias,
                                             void* __restrict__ out,
                                             float* __restrict__ stats, int n,
                                             int last) {
  __shared__ float lsum[16], lsq[16];
  const int t = threadIdx.x;
  const int slice = blockIdx.x & 7;
  if (!last) {
    if (t < 16) {
      lsum[t] = 0.f;
      lsq[t] = 0.f;
    }
    __syncthreads();
  }
  const int wave = t >> 6, lane = t & 63;
  const int g = lane >> 2;              // edge group 0..15
  const int c = lane & 3;               // channel sublane (4 ch)
  const unsigned int c8 = (unsigned int)c * 8u;
  const char* hbs = hb + (size_t)slice * (size_t)n * 32;  // this slice's plane
  // per-lane bias (channels slice*16 + c*4 .. +3), hoisted out of node loop
  float4 bv = *(const float4*)(bias + slice * 16 + c * 4);

  union HU { uint2 u; _Float16 h[4]; };

  const int nstreams = (gridDim.x >> 3) * 4;        // node streams per slice
  const int sid = (blockIdx.x >> 3) * 4 + wave;     // this wave's stream id

  for (int nd = sid; nd < n; nd += nstreams) {
    int e0 = row_ptr[nd], e1 = row_ptr[nd + 1];  // length >=16, mult of 16
    float a0 = 0.f, a1 = 0.f, a2 = 0.f, a3 = 0.f;
    uint2 m = ldnt_u2(&eh[e0 + g]);
    for (int e = e0; e < e1;) {
      HU u;
      u.u = *(const uint2*)(hbs + (m.x + c8));
      int en = e + 16;
      int ep = (en < e1) ? en : e;  // clamp: harmless reload on last window
      uint2 mn = ldnt_u2(&eh[ep + g]);
      float w = __uint_as_float(m.y);
      a0 = fmaf((float)u.h[0], w, a0);
      a1 = fmaf((float)u.h[1], w, a1);
      a2 = fmaf((float)u.h[2], w, a2);
      a3 = fmaf((float)u.h[3], w, a3);
      m = mn;
      e = en;
    }
    // reduce across edge groups (lane bits 2..5)
#pragma unroll
    for (int mk = 4; mk <= 32; mk <<= 1) {
      a0 += __shfl_xor(a0, mk);
      a1 += __shfl_xor(a1, mk);
      a2 += __shfl_xor(a2, mk);
      a3 += __shfl_xor(a3, mk);
    }
    if (g == 0) {  // lanes 0-3 hold the 16 channels (4 each)
      a0 += bv.x;
      a1 += bv.y;
      a2 += bv.z;
      a3 += bv.w;
      if (last) {
        float4 o = {a0, a1, a2, a3};
        *(float4*)((float*)out + (size_t)nd * 128 + slice * 16 + c * 4) = o;
      } else {
        uint2 o;
        o.x = packh(a0, a1);
        o.y = packh(a2, a3);
        char* op = (char*)out + (size_t)slice * (size_t)n * 32 + (size_t)nd * 32;
        __builtin_nontemporal_store(((unsigned long long)o.y << 32) | o.x,
                                    (unsigned long long*)(op + c * 8));
        atomicAdd(&lsum[c * 4 + 0], a0);
        atomicAdd(&lsum[c * 4 + 1], a1);
        atomicAdd(&lsum[c * 4 + 2], a2);
        atomicAdd(&lsum[c * 4 + 3], a3);
        atomicAdd(&lsq[c * 4 + 0], a0 * a0);
        atomicAdd(&lsq[c * 4 + 1], a1 * a1);
        atomicAdd(&lsq[c * 4 + 2], a2 * a2);
        atomicAdd(&lsq[c * 4 + 3], a3 * a3);
      }
    }
  }
  if (!last) {
    __syncthreads();
    if (t < 16)
      atomicAdd(&stats[slice * 16 + t], lsum[t]);
    else if (t < 32)
      atomicAdd(&stats[128 + slice * 16 + (t - 16)], lsq[t - 16]);
  }
}

// ---------------------------------------------------------------------------
extern "C" void kernel_launch(void* const* d_in, const int* in_sizes, int n_in,
                              void* d_out, int out_size, void* d_ws, size_t ws_size,
                              hipStream_t stream) {
  const float* x_in = (const float*)d_in[0];
  const int* ei = (const int*)d_in[1];
  const float* W0 = (const float*)d_in[2];
  const float* b0 = (const float*)d_in[3];
  const float* Wmid = (const float*)d_in[4];
  const float* bmid = (const float*)d_in[5];
  const float* Wlast = (const float*)d_in[6];
  const float* blast = (const float*)d_in[7];
  const float* gamma = (const float*)d_in[8];
  const float* beta = (const float*)d_in[9];

  const int n = in_sizes[0] / D;  // 100000
  const int e = in_sizes[1] / 2;  // 1600000
  const int ec = e + 16 * n;      // padded-edge capacity (deg+1, pad-16)

  // ---- workspace carve-out ----
  char* ws = (char*)d_ws;
  size_t off = 0;
  auto alloc = [&](size_t bytes) -> void* {
    void* p = ws + off;
    off += (bytes + 255) & ~(size_t)255;
    return p;
  };
  unsigned int* XhA = (unsigned int*)alloc((size_t)n * 64 * 4);  // fp16 x ping
  unsigned int* XhB = (unsigned int*)alloc((size_t)n * 64 * 4);  // fp16 x pong
  unsigned int* Hh = (unsigned int*)alloc((size_t)n * 64 * 4);   // fp16 h (sliced)
  unsigned int* Ag = (unsigned int*)alloc((size_t)n * 64 * 4);   // fp16 agg (sliced)
  ushort_t* Wf = (ushort_t*)alloc((size_t)6 * 16384 * 2);
  int* row_ptr = (int*)alloc((size_t)(n + 1) * 4);
  int* excl = (int*)alloc((size_t)n * 4);
  float* dinv = (float*)alloc((size_t)n * 4);
  int* bsum = (int*)alloc(1024);
  int* flag = (int*)alloc(256);
  // zeroed region: eh | cnt | fill | stats  (single memset; pad metas = {0,0})
  char* zbase = ws + off;
  uint2* eh = (uint2*)alloc((size_t)ec * 8);
  int* cnt = (int*)alloc((size_t)n * 4);
  int* fill = (int*)alloc((size_t)n * 4);
  float* stats = (float*)alloc(5 * 256 * 4);
  size_t zbytes = (size_t)((ws + off) - zbase);
  hipMemsetAsync(zbase, 0, zbytes, stream);

  // ---- graph prep ----
  k_detect<<<1, 64, 0, stream>>>(ei, flag);
  int eb = (e + 255) / 256;
  k_hist<<<eb, 256, 0, stream>>>(ei, cnt, flag, e);
  int nb1024 = (n + 1023) / 1024;
  k_scan1<<<nb1024, 256, 0, stream>>>(cnt, excl, bsum, n);
  k_scan2<<<1, 64, 0, stream>>>(bsum, nb1024, row_ptr, n);
  int nb256 = (n + 255) / 256;
  k_scan3<<<nb256, 256, 0, stream>>>(excl, bsum, row_ptr, n);
  k_dinv<<<nb256, 256, 0, stream>>>(cnt, dinv, n);
  k_scatter<<<eb, 256, 0, stream>>>(ei, row_ptr, fill, dinv, eh, flag, e);
  k_self<<<nb256, 256, 0, stream>>>(cnt, row_ptr, dinv, eh, n);
  k_wconv<<<(6 * 16384 + 255) / 256, 256, 0, stream>>>(W0, Wmid, Wlast, Wf);

  // ---- layers ----
  const int gemm_blocks = (n + 127) / 128;
  const int agg_blocks = 2048;  // &7 = slice (XCD-affine), >>3 = node block

  // layer 0
  k_gemm<<<gemm_blocks, 256, 0, stream>>>(x_in, Wf, (ushort_t*)Hh, nullptr,
                                          nullptr, nullptr, nullptr, nullptr, n, 0);
  k_agg<<<agg_blocks, 256, 0, stream>>>((const char*)Hh, row_ptr, eh, b0, Ag,
                                        stats, n, 0);
  // layers 1..4 (gemm_L fuses BN/relu/residual of layer L-1)
  unsigned int* xprev = nullptr;
  unsigned int* xnew = XhA;
  for (int L = 1; L <= 4; L++) {
    const float* bL = bmid + (size_t)(L - 1) * D;
    k_gemm<<<gemm_blocks, 256, 0, stream>>>(
        Ag, Wf + (size_t)L * 16384, (ushort_t*)Hh, xnew, xprev,
        stats + (L - 1) * 256, gamma + (L - 1) * D, beta + (L - 1) * D, n,
        (L == 1) ? 1 : 2);
    k_agg<<<agg_blocks, 256, 0, stream>>>((const char*)Hh, row_ptr, eh, bL, Ag,
                                          stats + L * 256, n, 0);
    xprev = xnew;
    xnew = (xnew == XhA) ? XhB : XhA;
  }
  // output layer (gemm_5 fuses BN/relu/residual of layer 4)
  k_gemm<<<gemm_blocks, 256, 0, stream>>>(Ag, Wf + (size_t)5 * 16384,
                                          (ushort_t*)Hh, xnew, xprev,
                                          stats + 4 * 256, gamma + 4 * D,
                                          beta + 4 * D, n, 2);
  k_agg<<<agg_blocks, 256, 0, stream>>>((const char*)Hh, row_ptr, eh, blast,
                                        d_out, nullptr, n, 1);
}

// Round 4
// 1616.597 us; speedup vs baseline: 1.3766x; 1.3766x over previous
//
#include <hip/hip_runtime.h>

#define D 128
#define BN_EPS 1e-5f

typedef _Float16 half8 __attribute__((ext_vector_type(8)));
typedef float f32x4 __attribute__((ext_vector_type(4)));
typedef unsigned short ushort_t;

// ---------------- fp16 pack/unpack helpers ----------------
__device__ __forceinline__ unsigned short f2h(float f) {
  union { _Float16 h; unsigned short u; } c;
  c.h = (_Float16)f;  // RNE
  return c.u;
}
__device__ __forceinline__ unsigned int packh(float lo, float hi) {
  return (unsigned int)f2h(lo) | ((unsigned int)f2h(hi) << 16);
}
__device__ __forceinline__ float h2f(unsigned int v) {
  union { unsigned short u; _Float16 h; } c;
  c.u = (unsigned short)v;
  return (float)c.h;
}
// non-temporal 8B load (edge-meta stream: don't evict the L2-resident h slice)
__device__ __forceinline__ uint2 ldnt_u2(const uint2* p) {
  union { unsigned long long q; uint2 v; } c;
  c.q = __builtin_nontemporal_load((const unsigned long long*)p);
  return c.v;
}

// ---------------------------------------------------------------------------
// Edge dtype sniffer (int64 vs int32 edge_index)
// ---------------------------------------------------------------------------
__global__ void k_detect(const int* __restrict__ ei, int* __restrict__ flag) {
  if (blockIdx.x == 0 && threadIdx.x == 0) {
    int is64 = 1;
    for (int i = 0; i < 16; i++)
      if (ei[2 * i + 1] != 0) is64 = 0;
    *flag = is64;
  }
}
__device__ __forceinline__ int load_src(const int* ei, int e, int i, int is64) {
  return is64 ? ei[2 * i] : ei[i];
}
__device__ __forceinline__ int load_dst(const int* ei, int e, int i, int is64) {
  return is64 ? ei[2 * e + 2 * i] : ei[e + i];
}

// ---------------------------------------------------------------------------
// Graph prep. Rows are EXACTLY deg+1 slots (self-loop materialized as a real
// edge, NO padding). Row ends handled in k_agg by per-lane clamp+zero-weight.
// ---------------------------------------------------------------------------
__global__ void k_hist(const int* __restrict__ ei, int* __restrict__ cnt,
                       const int* __restrict__ flag, int e) {
  int i = blockIdx.x * blockDim.x + threadIdx.x;
  if (i < e) {
    int d = load_dst(ei, e, i, *flag);
    atomicAdd(&cnt[d], 1);
  }
}

__global__ void k_scan1(const int* __restrict__ cnt, int* __restrict__ excl,
                        int* __restrict__ bsum, int n) {
  __shared__ int s[256];
  int t = threadIdx.x;
  int base = blockIdx.x * 1024;
  int v[4];
  int tot = 0;
#pragma unroll
  for (int i = 0; i < 4; i++) {
    int idx = base + t * 4 + i;
    v[i] = (idx < n) ? (cnt[idx] + 1) : 0;  // deg+1 (self), exact
    tot += v[i];
  }
  s[t] = tot;
  __syncthreads();
#pragma unroll
  for (int off = 1; off < 256; off <<= 1) {
    int x = (t >= off) ? s[t - off] : 0;
    __syncthreads();
    s[t] += x;
    __syncthreads();
  }
  int run = s[t] - tot;
#pragma unroll
  for (int i = 0; i < 4; i++) {
    int idx = base + t * 4 + i;
    if (idx < n) excl[idx] = run;
    run += v[i];
  }
  if (t == 255) bsum[blockIdx.x] = s[255];
}

__global__ void k_scan2(int* bsum, int nb, int* row_ptr, int n) {
  if (blockIdx.x == 0 && threadIdx.x == 0) {
    int run = 0;
    for (int i = 0; i < nb; i++) {
      int t = bsum[i];
      bsum[i] = run;
      run += t;
    }
    row_ptr[n] = run;
  }
}

__global__ void k_scan3(const int* __restrict__ excl, const int* __restrict__ bsum,
                        int* __restrict__ row_ptr, int n) {
  int i = blockIdx.x * blockDim.x + threadIdx.x;
  if (i < n) row_ptr[i] = excl[i] + bsum[i >> 10];
}

__global__ void k_dinv(const int* __restrict__ cnt, float* __restrict__ dinv, int n) {
  int i = blockIdx.x * blockDim.x + threadIdx.x;
  if (i < n) dinv[i] = rsqrtf((float)(cnt[i] + 1));  // +1 self loop
}

// Edge meta: {.x = src*32 (byte offset into a 32B slice chunk), .y = w bits}
__global__ void k_scatter(const int* __restrict__ ei, const int* __restrict__ row_ptr,
                          int* __restrict__ fill, const float* __restrict__ dinv,
                          uint2* __restrict__ eh, const int* __restrict__ flag,
                          int e) {
  int i = blockIdx.x * blockDim.x + threadIdx.x;
  if (i < e) {
    int is64 = *flag;
    int s = load_src(ei, e, i, is64);
    int d = load_dst(ei, e, i, is64);
    int pos = row_ptr[d] + atomicAdd(&fill[d], 1);
    uint2 m;
    m.x = (unsigned int)s * 32u;
    m.y = __float_as_uint(dinv[s] * dinv[d]);
    eh[pos] = m;
  }
}

// self-loop edge at row_ptr[i]+cnt[i] = last slot of row i
__global__ void k_self(const int* __restrict__ cnt, const int* __restrict__ row_ptr,
                       const float* __restrict__ dinv, uint2* __restrict__ eh,
                       int n) {
  int i = blockIdx.x * blockDim.x + threadIdx.x;
  if (i < n) {
    float di = dinv[i];
    uint2 m;
    m.x = (unsigned int)i * 32u;
    m.y = __float_as_uint(di * di);
    eh[row_ptr[i] + cnt[i]] = m;
  }
}

// ---------------------------------------------------------------------------
// W fp32 -> fp16 in MFMA-B-fragment-major layout: Wf[l][(k>>3)*128 + c][k&7]
// ---------------------------------------------------------------------------
__global__ void k_wconv(const float* __restrict__ W0, const float* __restrict__ Wmid,
                        const float* __restrict__ Wlast, ushort_t* __restrict__ Wf) {
  int i = blockIdx.x * 256 + threadIdx.x;
  if (i >= 6 * 16384) return;
  int l = i >> 14, r = i & 16383;
  int k = r >> 7, c = r & 127;
  const float* W = (l == 0) ? W0 : (l <= 4 ? Wmid + (size_t)(l - 1) * 16384 : Wlast);
  Wf[(size_t)l * 16384 + (((k >> 3) * 128 + c) << 3) + (k & 7)] = f2h(W[r]);
}

// ---------------------------------------------------------------------------
// Fused GEMM: x = epilogue(src) ; H = x @ W.
// fp16 feature tensors (Hh, Ag) are SLICE-MAJOR: [slice(=ch>>4)][node][16ch],
// 32B per node per slice -> aggregation working set per slice = n*32B = 3.2MB
// < 4MB (one XCD's L2).
//   mode 0: x = fp32 src (raw input, [node][128]), no BN, no Xh write
//   mode 1: x = relu(bn(src_sliced_fp16)); write XhNew
//   mode 2: x = relu(bn(src_sliced_fp16)) + XhPrev; write XhNew
// XhNew/XhPrev (residual stream) stay in [node][128] fp16-packed layout.
// ---------------------------------------------------------------------------
__global__ __launch_bounds__(256) void k_gemm(
    const void* __restrict__ src, const ushort_t* __restrict__ Wf,
    ushort_t* __restrict__ Hh, unsigned int* __restrict__ XhNew,
    const unsigned int* __restrict__ XhPrev, const float* __restrict__ stats,
    const float* __restrict__ gamma, const float* __restrict__ beta, int n,
    int mode) {
  __shared__ ushort_t As[16384];
  __shared__ ushort_t Ws[16384];
  const int t = threadIdx.x;
  const int rowBase = blockIdx.x * 128;
  const int off = t & 15;  // channel octet this thread stages (all 8 chunks)
  const size_t slice_stride = (size_t)n * 32;  // bytes per slice plane

  float sc[8], sh[8];
  if (mode >= 1) {
    float inv_n = 1.0f / (float)n;
#pragma unroll
    for (int j = 0; j < 8; j++) {
      int ch = off * 8 + j;
      float mean = stats[ch] * inv_n;
      float var = stats[128 + ch] * inv_n - mean * mean;
      if (var < 0.f) var = 0.f;
      float is = rsqrtf(var + BN_EPS);
      float s = gamma[ch] * is;
      sc[j] = s;
      sh[j] = beta[ch] - mean * s;
    }
  }

#pragma unroll
  for (int i = 0; i < 8; i++) {
    int c = t + i * 256;
    int row = c >> 4;
    int grow = rowBase + row;
    bool valid = grow < n;
    if (!valid) grow = n - 1;
    unsigned int pk[4];
    if (mode == 0) {
      const float* xp = (const float*)src + (size_t)grow * 128 + off * 8;
      float4 v0 = *(const float4*)xp;
      float4 v1 = *(const float4*)(xp + 4);
      pk[0] = packh(v0.x, v0.y);
      pk[1] = packh(v0.z, v0.w);
      pk[2] = packh(v1.x, v1.y);
      pk[3] = packh(v1.z, v1.w);
    } else {
      // sliced read: channels off*8..off*8+7 live in slice off>>1,
      // byte offset (off&1)*16 within the node's 32B chunk
      const char* ap = (const char*)src + (size_t)(off >> 1) * slice_stride +
                       (size_t)grow * 32 + (off & 1) * 16;
      uint4 av = *(const uint4*)ap;
      float v[8];
      v[0] = h2f(av.x & 0xffff); v[1] = h2f(av.x >> 16);
      v[2] = h2f(av.y & 0xffff); v[3] = h2f(av.y >> 16);
      v[4] = h2f(av.z & 0xffff); v[5] = h2f(av.z >> 16);
      v[6] = h2f(av.w & 0xffff); v[7] = h2f(av.w >> 16);
#pragma unroll
      for (int j = 0; j < 8; j++) v[j] = fmaxf(v[j] * sc[j] + sh[j], 0.f);
      if (mode == 2) {
        uint4 rv = *(const uint4*)(XhPrev + (size_t)grow * 64 + off * 4);
        v[0] += h2f(rv.x & 0xffff); v[1] += h2f(rv.x >> 16);
        v[2] += h2f(rv.y & 0xffff); v[3] += h2f(rv.y >> 16);
        v[4] += h2f(rv.z & 0xffff); v[5] += h2f(rv.z >> 16);
        v[6] += h2f(rv.w & 0xffff); v[7] += h2f(rv.w >> 16);
      }
      pk[0] = packh(v[0], v[1]);
      pk[1] = packh(v[2], v[3]);
      pk[2] = packh(v[4], v[5]);
      pk[3] = packh(v[6], v[7]);
      if (valid) *(uint4*)(XhNew + (size_t)grow * 64 + off * 4) = *(uint4*)pk;
    }
    *(uint4*)(&As[(off * 128 + row) * 8]) = *(uint4*)pk;
  }
#pragma unroll
  for (int i = 0; i < 8; i++) {
    int c = t + i * 256;
    *(uint4*)(&Ws[c * 8]) = *(const uint4*)(Wf + c * 8);
  }
  __syncthreads();

  const int wave = t >> 6, lane = t & 63;
  const int q = lane >> 4, ln = lane & 15;
  const int m0 = wave * 32;

  f32x4 acc[2][8];
#pragma unroll
  for (int mt = 0; mt < 2; mt++)
#pragma unroll
    for (int nt = 0; nt < 8; nt++) acc[mt][nt] = (f32x4){0.f, 0.f, 0.f, 0.f};

#pragma unroll
  for (int kk = 0; kk < 4; kk++) {
    int kg = kk * 4 + q;
    half8 a[2];
#pragma unroll
    for (int mt = 0; mt < 2; mt++)
      a[mt] = *(const half8*)(&As[(kg * 128 + m0 + mt * 16 + ln) * 8]);
    half8 b[8];
#pragma unroll
    for (int nt = 0; nt < 8; nt++)
      b[nt] = *(const half8*)(&Ws[(kg * 128 + nt * 16 + ln) * 8]);
#pragma unroll
    for (int mt = 0; mt < 2; mt++)
#pragma unroll
      for (int nt = 0; nt < 8; nt++)
        acc[mt][nt] =
            __builtin_amdgcn_mfma_f32_16x16x32_f16(a[mt], b[nt], acc[mt][nt], 0, 0, 0);
  }

  // sliced store: channel nt*16+ln -> slice nt, pos ln
#pragma unroll
  for (int mt = 0; mt < 2; mt++) {
#pragma unroll
    for (int r = 0; r < 4; r++) {
      int grow = rowBase + m0 + mt * 16 + q * 4 + r;
      if (grow < n) {
#pragma unroll
        for (int nt = 0; nt < 8; nt++) {
          ushort_t* hp = (ushort_t*)((char*)Hh + (size_t)nt * slice_stride +
                                     (size_t)grow * 32);
          hp[ln] = f2h(acc[mt][nt][r]);
        }
      }
    }
  }
}

// ---------------------------------------------------------------------------
// CHANNEL-SLICED aggregation, XCD-affine, DEEP-PIPELINED (R4).
// slice = blockIdx.x & 7 == XCD id under round-robin dispatch: that XCD's L2
// holds the whole slice plane (3.2MB) -> gathers are L2 hits (R3 FETCH proof).
// R3's mistake (1 gather in flight) fixed: each wave processes 4 NODES
// concurrently, 2 x 16-edge windows each, all 8 meta loads + 8 gathers
// issued back-to-back -> 8 independent requests in flight at L2 latency.
// Rows are exact deg+1 (no padding); per-lane clamp + zero-weight handles
// row ends; rare rows >32 take a tail loop. NAMED SCALARS via macros only.
// Lane l: c = l&3 (4 fp16 ch = 8B of the 32B chunk), el = l>>2 (edge slot
// 0..15). Reduce over lane bits 2..5; lanes 0-3 write; BN stats accumulate
// in registers, flushed once per block via LDS.
// last=0: fp16 sliced out + BN stats.  last=1: fp32 [node][128] out.
// ---------------------------------------------------------------------------
#define ACC_INIT(J) float a0_##J = 0.f, a1_##J = 0.f, a2_##J = 0.f, a3_##J = 0.f;

#define NODE_SETUP(J)        \
  int nd_##J = base + J;     \
  bool nv_##J = nd_##J < n;  \
  if (!nv_##J) nd_##J = n - 1; \
  int e0_##J = row_ptr[nd_##J]; \
  int e1_##J = row_ptr[nd_##J + 1];

#define WIN_META(J, W, OFS)                         \
  int ia_##J##W = e0_##J + (OFS) + el;              \
  bool va_##J##W = ia_##J##W < e1_##J;              \
  int ic_##J##W = va_##J##W ? ia_##J##W : (e1_##J - 1); \
  uint2 m_##J##W = ldnt_u2(&eh[ic_##J##W]);

#define WIN_GATH(J, W) \
  HU g_##J##W;         \
  g_##J##W.u = *(const uint2*)(hbs + (m_##J##W.x + c8));

#define WIN_FMA(J, W)                                          \
  {                                                            \
    float w_ = va_##J##W ? __uint_as_float(m_##J##W.y) : 0.f;  \
    a0_##J = fmaf((float)g_##J##W.h[0], w_, a0_##J);           \
    a1_##J = fmaf((float)g_##J##W.h[1], w_, a1_##J);           \
    a2_##J = fmaf((float)g_##J##W.h[2], w_, a2_##J);           \
    a3_##J = fmaf((float)g_##J##W.h[3], w_, a3_##J);           \
  }

#define WIN_TAIL(J)                                      \
  for (int eo = e0_##J + 32; eo < e1_##J; eo += 16) {    \
    int it_ = eo + el;                                   \
    bool vt_ = it_ < e1_##J;                             \
    int itc_ = vt_ ? it_ : (e1_##J - 1);                 \
    uint2 mt_ = ldnt_u2(&eh[itc_]);                      \
    float wt_ = vt_ ? __uint_as_float(mt_.y) : 0.f;      \
    HU gt_;                                              \
    gt_.u = *(const uint2*)(hbs + (mt_.x + c8));         \
    a0_##J = fmaf((float)gt_.h[0], wt_, a0_##J);         \
    a1_##J = fmaf((float)gt_.h[1], wt_, a1_##J);         \
    a2_##J = fmaf((float)gt_.h[2], wt_, a2_##J);         \
    a3_##J = fmaf((float)gt_.h[3], wt_, a3_##J);         \
  }

#define NODE_RED(J)                    \
  a0_##J += __shfl_xor(a0_##J, 4);     \
  a1_##J += __shfl_xor(a1_##J, 4);     \
  a2_##J += __shfl_xor(a2_##J, 4);     \
  a3_##J += __shfl_xor(a3_##J, 4);     \
  a0_##J += __shfl_xor(a0_##J, 8);     \
  a1_##J += __shfl_xor(a1_##J, 8);     \
  a2_##J += __shfl_xor(a2_##J, 8);     \
  a3_##J += __shfl_xor(a3_##J, 8);     \
  a0_##J += __shfl_xor(a0_##J, 16);    \
  a1_##J += __shfl_xor(a1_##J, 16);    \
  a2_##J += __shfl_xor(a2_##J, 16);    \
  a3_##J += __shfl_xor(a3_##J, 16);    \
  a0_##J += __shfl_xor(a0_##J, 32);    \
  a1_##J += __shfl_xor(a1_##J, 32);    \
  a2_##J += __shfl_xor(a2_##J, 32);    \
  a3_##J += __shfl_xor(a3_##J, 32);

#define NODE_OUT(J)                                                          \
  if (el == 0 && nv_##J) {                                                   \
    a0_##J += bv.x;                                                          \
    a1_##J += bv.y;                                                          \
    a2_##J += bv.z;                                                          \
    a3_##J += bv.w;                                                          \
    if (last) {                                                              \
      float4 o = {a0_##J, a1_##J, a2_##J, a3_##J};                           \
      *(float4*)((float*)out + (size_t)nd_##J * 128 + slice * 16 + c * 4) = o; \
    } else {                                                                 \
      uint2 o;                                                               \
      o.x = packh(a0_##J, a1_##J);                                           \
      o.y = packh(a2_##J, a3_##J);                                           \
      char* op = (char*)out + slice_plane + (size_t)nd_##J * 32 + c8;        \
      __builtin_nontemporal_store(((unsigned long long)o.y << 32) | o.x,     \
                                  (unsigned long long*)op);                  \
      rs0 += a0_##J; rs1 += a1_##J; rs2 += a2_##J; rs3 += a3_##J;            \
      rq0 += a0_##J * a0_##J; rq1 += a1_##J * a1_##J;                        \
      rq2 += a2_##J * a2_##J; rq3 += a3_##J * a3_##J;                        \
    }                                                                        \
  }

__global__ __launch_bounds__(256) void k_agg(const char* __restrict__ hb,
                                             const int* __restrict__ row_ptr,
                                             const uint2* __restrict__ eh,
                                             const float* __restrict__ bias,
                                             void* __restrict__ out,
                                             float* __restrict__ stats, int n,
                                             int last) {
  __shared__ float lsum[16], lsq[16];
  const int t = threadIdx.x;
  const int slice = blockIdx.x & 7;
  if (!last) {
    if (t < 16) {
      lsum[t] = 0.f;
      lsq[t] = 0.f;
    }
    __syncthreads();
  }
  const int wave = t >> 6, lane = t & 63;
  const int c = lane & 3;   // channel sublane (4 ch = 8B)
  const int el = lane >> 2; // edge slot 0..15
  const unsigned int c8 = (unsigned int)c * 8u;
  const size_t slice_plane = (size_t)slice * (size_t)n * 32;
  const char* hbs = hb + slice_plane;
  float4 bv = *(const float4*)(bias + slice * 16 + c * 4);
  float rs0 = 0.f, rs1 = 0.f, rs2 = 0.f, rs3 = 0.f;
  float rq0 = 0.f, rq1 = 0.f, rq2 = 0.f, rq3 = 0.f;

  union HU { uint2 u; _Float16 h[4]; };

  const int nstreams = (gridDim.x >> 3) * 4;     // wave-streams per slice
  const int sid = (blockIdx.x >> 3) * 4 + wave;  // this wave's stream id

  for (int base = sid * 4; base < n; base += nstreams * 4) {
    NODE_SETUP(0) NODE_SETUP(1) NODE_SETUP(2) NODE_SETUP(3)
    ACC_INIT(0) ACC_INIT(1) ACC_INIT(2) ACC_INIT(3)
    // issue all 8 meta loads
    WIN_META(0, A, 0) WIN_META(1, A, 0) WIN_META(2, A, 0) WIN_META(3, A, 0)
    WIN_META(0, B, 16) WIN_META(1, B, 16) WIN_META(2, B, 16) WIN_META(3, B, 16)
    // issue all 8 gathers (each depends only on its own meta)
    WIN_GATH(0, A) WIN_GATH(1, A) WIN_GATH(2, A) WIN_GATH(3, A)
    WIN_GATH(0, B) WIN_GATH(1, B) WIN_GATH(2, B) WIN_GATH(3, B)
    // accumulate
    WIN_FMA(0, A) WIN_FMA(1, A) WIN_FMA(2, A) WIN_FMA(3, A)
    WIN_FMA(0, B) WIN_FMA(1, B) WIN_FMA(2, B) WIN_FMA(3, B)
    // rare rows > 32
    WIN_TAIL(0) WIN_TAIL(1) WIN_TAIL(2) WIN_TAIL(3)
    // reduce over edge slots (lane bits 2..5) and write
    NODE_RED(0) NODE_RED(1) NODE_RED(2) NODE_RED(3)
    NODE_OUT(0) NODE_OUT(1) NODE_OUT(2) NODE_OUT(3)
  }

  if (!last) {
    if (el == 0) {
      atomicAdd(&lsum[c * 4 + 0], rs0);
      atomicAdd(&lsum[c * 4 + 1], rs1);
      atomicAdd(&lsum[c * 4 + 2], rs2);
      atomicAdd(&lsum[c * 4 + 3], rs3);
      atomicAdd(&lsq[c * 4 + 0], rq0);
      atomicAdd(&lsq[c * 4 + 1], rq1);
      atomicAdd(&lsq[c * 4 + 2], rq2);
      atomicAdd(&lsq[c * 4 + 3], rq3);
    }
    __syncthreads();
    if (t < 16) {
      atomicAdd(&stats[slice * 16 + t], lsum[t]);
      atomicAdd(&stats[128 + slice * 16 + t], lsq[t]);
    }
  }
}

// ---------------------------------------------------------------------------
extern "C" void kernel_launch(void* const* d_in, const int* in_sizes, int n_in,
                              void* d_out, int out_size, void* d_ws, size_t ws_size,
                              hipStream_t stream) {
  const float* x_in = (const float*)d_in[0];
  const int* ei = (const int*)d_in[1];
  const float* W0 = (const float*)d_in[2];
  const float* b0 = (const float*)d_in[3];
  const float* Wmid = (const float*)d_in[4];
  const float* bmid = (const float*)d_in[5];
  const float* Wlast = (const float*)d_in[6];
  const float* blast = (const float*)d_in[7];
  const float* gamma = (const float*)d_in[8];
  const float* beta = (const float*)d_in[9];

  const int n = in_sizes[0] / D;  // 100000
  const int e = in_sizes[1] / 2;  // 1600000
  const int ec = e + n;           // exact slot count (deg+1 per node)

  // ---- workspace carve-out ----
  char* ws = (char*)d_ws;
  size_t off = 0;
  auto alloc = [&](size_t bytes) -> void* {
    void* p = ws + off;
    off += (bytes + 255) & ~(size_t)255;
    return p;
  };
  unsigned int* XhA = (unsigned int*)alloc((size_t)n * 64 * 4);  // fp16 x ping
  unsigned int* XhB = (unsigned int*)alloc((size_t)n * 64 * 4);  // fp16 x pong
  unsigned int* Hh = (unsigned int*)alloc((size_t)n * 64 * 4);   // fp16 h (sliced)
  unsigned int* Ag = (unsigned int*)alloc((size_t)n * 64 * 4);   // fp16 agg (sliced)
  ushort_t* Wf = (ushort_t*)alloc((size_t)6 * 16384 * 2);
  int* row_ptr = (int*)alloc((size_t)(n + 1) * 4);
  int* excl = (int*)alloc((size_t)n * 4);
  float* dinv = (float*)alloc((size_t)n * 4);
  int* bsum = (int*)alloc(1024);
  int* flag = (int*)alloc(256);
  uint2* eh = (uint2*)alloc((size_t)ec * 8);  // fully written, no memset needed
  // zeroed region: cnt | fill | stats  (single memset)
  char* zbase = ws + off;
  int* cnt = (int*)alloc((size_t)n * 4);
  int* fill = (int*)alloc((size_t)n * 4);
  float* stats = (float*)alloc(5 * 256 * 4);
  size_t zbytes = (size_t)((ws + off) - zbase);
  hipMemsetAsync(zbase, 0, zbytes, stream);

  // ---- graph prep ----
  k_detect<<<1, 64, 0, stream>>>(ei, flag);
  int eb = (e + 255) / 256;
  k_hist<<<eb, 256, 0, stream>>>(ei, cnt, flag, e);
  int nb1024 = (n + 1023) / 1024;
  k_scan1<<<nb1024, 256, 0, stream>>>(cnt, excl, bsum, n);
  k_scan2<<<1, 64, 0, stream>>>(bsum, nb1024, row_ptr, n);
  int nb256 = (n + 255) / 256;
  k_scan3<<<nb256, 256, 0, stream>>>(excl, bsum, row_ptr, n);
  k_dinv<<<nb256, 256, 0, stream>>>(cnt, dinv, n);
  k_scatter<<<eb, 256, 0, stream>>>(ei, row_ptr, fill, dinv, eh, flag, e);
  k_self<<<nb256, 256, 0, stream>>>(cnt, row_ptr, dinv, eh, n);
  k_wconv<<<(6 * 16384 + 255) / 256, 256, 0, stream>>>(W0, Wmid, Wlast, Wf);

  // ---- layers ----
  const int gemm_blocks = (n + 127) / 128;
  const int agg_blocks = 1792;  // 8 slices x 224 blocks = 7 blocks/CU

  // layer 0
  k_gemm<<<gemm_blocks, 256, 0, stream>>>(x_in, Wf, (ushort_t*)Hh, nullptr,
                                          nullptr, nullptr, nullptr, nullptr, n, 0);
  k_agg<<<agg_blocks, 256, 0, stream>>>((const char*)Hh, row_ptr, eh, b0, Ag,
                                        stats, n, 0);
  // layers 1..4 (gemm_L fuses BN/relu/residual of layer L-1)
  unsigned int* xprev = nullptr;
  unsigned int* xnew = XhA;
  for (int L = 1; L <= 4; L++) {
    const float* bL = bmid + (size_t)(L - 1) * D;
    k_gemm<<<gemm_blocks, 256, 0, stream>>>(
        Ag, Wf + (size_t)L * 16384, (ushort_t*)Hh, xnew, xprev,
        stats + (L - 1) * 256, gamma + (L - 1) * D, beta + (L - 1) * D, n,
        (L == 1) ? 1 : 2);
    k_agg<<<agg_blocks, 256, 0, stream>>>((const char*)Hh, row_ptr, eh, bL, Ag,
                                          stats + L * 256, n, 0);
    xprev = xnew;
    xnew = (xnew == XhA) ? XhB : XhA;
  }
  // output layer (gemm_5 fuses BN/relu/residual of layer 4)
  k_gemm<<<gemm_blocks, 256, 0, stream>>>(Ag, Wf + (size_t)5 * 16384,
                                          (ushort_t*)Hh, xnew, xprev,
                                          stats + 4 * 256, gamma + 4 * D,
                                          beta + 4 * D, n, 2);
  k_agg<<<agg_blocks, 256, 0, stream>>>((const char*)Hh, row_ptr, eh, blast,
                                        d_out, nullptr, n, 1);
}